// Round 8
// baseline (27.200 us; speedup 1.0000x reference)
//
#include <hip/hip_runtime.h>
#include <hip/hip_fp16.h>

#define BATCH 4
#define HH 1024
#define WW 1024
#define GDp 8
#define NC 12
#define PAIR2 12    // half2 per z-pair cell: cells (z=p, z=p+1), 48 B, 16-B aligned
#define HROW2 268   // half2 per Hs row: 21*12=252 used, pad to 268 (1072 B)
#define NTILE 2     // 64x16 tiles per block (one 64x32 column)

union V4 { int4 i4; __half2 h[4]; };
typedef float f4 __attribute__((ext_vector_type(4)));

// Round-8 delta: TLP. Single-buffered Hs (wave-local build + in-order per-wave
// DS pipe makes this race-free without barriers) -> LDS 37.9->20.6 KB ->
// 7 blocks/CU = 28 waves (was 4 blocks/16 waves). Column halved to 64x32
// (2048 blocks) so 7/CU is fillable. Bet: 4 waves/SIMD cannot cover
// LDS+vmem latency of the in-order phase sequence; +75% TLP can.
__global__ __launch_bounds__(256, 7) void bsa_kernel(
    const float* __restrict__ grid,
    const float* __restrict__ guide,
    const float* __restrict__ image,
    float* __restrict__ out)
{
    __shared__ float sg[GDp][3][3][NC];                  // 3456 B
    __shared__ __align__(16) __half2 Hs2[16][HROW2];     // 17152 B (single buffer)

    const int bx  = blockIdx.x;   // 0..15
    const int byc = blockIdx.y;   // 0..31  (32-row column)
    const int b   = blockIdx.z;
    const int tx = threadIdx.x;   // 0..15
    const int ty = threadIdx.y;   // 0..15
    const int tid = ty * 16 + tx;
    const int lane = tid & 63;
    const int wv   = tid >> 6;    // wave id: owns Hs rows 4*wv .. 4*wv+3

    const int x0  = bx * 64;
    const int y0c = byc * 32;
    const float inv64 = 1.0f / 64.0f;

    // Column y-cell base: rows y0c..y0c+31 have floor(gy) in {ylo, ylo+1}.
    const float gy0c = (y0c + 0.5f) * inv64 - 0.5f;
    const int ylo = (int)floorf(gy0c);

    const int xloc = 4 * tx;
    const size_t plane = (size_t)HH * WW;
    const size_t gpix0 = ((size_t)(b * HH + y0c + ty)) * WW + x0 + xloc;
    const size_t ib0   = (size_t)b * 3 * plane + (size_t)(y0c + ty) * WW + x0 + xloc;

    // ---- tile-0 pixel IO: in flight under staging + build ----
    f4 cg  = *(const f4*)&guide[gpix0];
    f4 ci0 = *(const f4*)&image[ib0];
    f4 ci1 = *(const f4*)&image[ib0 + plane];
    f4 ci2 = *(const f4*)&image[ib0 + 2 * plane];

    // ---- stage grid slice once per block: o-pack channel permute ----
    {
        const int z = tid >> 5;        // 0..7
        const int u = tid & 31;        // active u<27
        if (u < 27) {
            const int cell = (u * 11) >> 5;      // u/3 (exact for u<32)
            const int cq   = u - cell * 3;       // u%3 -> channel quad
            const int yy   = (cell * 11) >> 5;   // cell/3 (exact, cell<9)
            const int xx   = cell - yy * 3;
            const int gxi = min(max(bx - 1 + xx, 0), 15);
            const int gyi = min(max(ylo + yy, 0), 15);
            const float* gp = grid + (size_t)b * (NC * GDp * 256)
                                   + ((size_t)z * 16 + gyi) * 16 + gxi;
#pragma unroll
            for (int j = 0; j < 4; ++j) {
                const int c = cq * 4 + j;
                // o-pack perm: pairs (c0,c4)(c1,c5)(c2,c6)(c3,c7)(c8,c9)(c10,c11)
                const int pos = (c < 8) ? ((c & 3) * 2 + (c >> 2)) : c;
                sg[z][yy][xx][pos] = gp[(size_t)c * (GDp * 256)];
            }
        }
    }
    __syncthreads();   // the ONLY block-wide barrier

    // ---- wave-local Hs build: wave wv builds rows 4wv..4wv+3 of tile t ----
    // Single buffer is safe: per-wave DS ops execute in order, so build(t+1)
    // writes (program-order after compute(t) reads) cannot pass them.
    auto build_hs = [&](int t) {
        for (int u = lane; u < 96; u += 64) {
            const int rl   = (u * 171) >> 12;    // u/24 (exact for u<96)
            const int cell = u - rl * 24;        // 0..23 = xs*8 + z
            const int r    = wv * 4 + rl;
            const int xs   = cell >> 3;
            const int z    = cell & 7;
            const float gy  = (y0c + t * 16 + r + 0.5f) * inv64 - 0.5f;
            const float fyf = floorf(gy);
            const float wy1 = gy - fyf;
            const float wy0 = 1.0f - wy1;
            const int ys0 = (int)fyf - ylo;          // 0 or 1 (column-wide)
            const float* s0 = &sg[z][ys0][xs][0];
            const float* s1 = &sg[z][ys0 + 1][xs][0];
            __half2 h[6];
#pragma unroll
            for (int m = 0; m < 6; ++m) {
                h[m] = __floats2half2_rn(wy0 * s0[2*m]   + wy1 * s1[2*m],
                                         wy0 * s0[2*m+1] + wy1 * s1[2*m+1]);
            }
            __half2* rowp = &Hs2[r][0];
            if (z < 7) {                 // first half of pair p=z
                __half2* hd = rowp + (xs * 7 + z) * PAIR2;
#pragma unroll
                for (int m = 0; m < 6; ++m) hd[m] = h[m];
            }
            if (z > 0) {                 // second half of pair p=z-1
                __half2* hd = rowp + (xs * 7 + (z - 1)) * PAIR2 + 6;
#pragma unroll
                for (int m = 0; m < 6; ++m) hd[m] = h[m];
            }
        }
    };

    build_hs(0);

    const int xs0 = tx >> 3;                     // 0 (x<32) or 1
    const float fxf = (float)(bx - 1 + xs0);
    const float gxb = (x0 + xloc + 0.5f) * inv64 - 0.5f;
    const __half oneh = __float2half_rn(1.0f);

#pragma unroll
    for (int t = 0; t < NTILE; ++t) {
        // ---- prefetch next tile's pixel IO (static regs; stays in flight) ----
        f4 ng, ni0, ni1, ni2;
        if (t < NTILE - 1) {
            const size_t gp = gpix0 + (size_t)(t + 1) * 16 * WW;
            const size_t ip = ib0   + (size_t)(t + 1) * 16 * WW;
            ng  = *(const f4*)&guide[gp];
            ni0 = *(const f4*)&image[ip];
            ni1 = *(const f4*)&image[ip + plane];
            ni2 = *(const f4*)&image[ip + 2 * plane];
        }

        // ---- per-pixel compute: 4 adjacent x px/thread ----
        const __half2* Hrow = &Hs2[ty][0];
        const size_t ib = ib0 + (size_t)t * 16 * WW;

        const float gk[4]  = {cg.x, cg.y, cg.z, cg.w};
        const float ia[4]  = {ci0.x, ci0.y, ci0.z, ci0.w};
        const float ja[4]  = {ci1.x, ci1.y, ci1.z, ci1.w};
        const float ka[4]  = {ci2.x, ci2.y, ci2.z, ci2.w};
        float ok0[4], ok1[4], ok2[4];

#pragma unroll
        for (int k = 0; k < 4; ++k) {
            const float wx1 = (gxb - fxf) + (float)k * inv64;
            const float wx0 = 1.0f - wx1;

            const float gz  = fmaf(gk[k], 8.0f, -0.5f);
            const float fzf = floorf(gz);
            const float zpf = fminf(fmaxf(fzf, 0.0f), 6.0f);      // v_med3
            const float whi = fminf(fmaxf(gz - zpf, 0.0f), 1.0f); // v_med3
            const float wlo = 1.0f - whi;
            const int zp = (int)zpf;

            const __half2 w00 = __float2half2_rn(wx0 * wlo);
            const __half2 w10 = __float2half2_rn(wx0 * whi);
            const __half2 w01 = __float2half2_rn(wx1 * wlo);
            const __half2 w11 = __float2half2_rn(wx1 * whi);

            // z-pair layout: 6 aligned ds_read_b128 cover all 4 corners
            const __half2* q = Hrow + (xs0 * 7 + zp) * PAIR2;
            V4 va, vb, vc, vd, ve, vf;
            va.i4 = *(const int4*)(q);           // A0..A3
            vb.i4 = *(const int4*)(q + 4);       // A4,A5,B0,B1
            vc.i4 = *(const int4*)(q + 8);       // B2..B5
            vd.i4 = *(const int4*)(q + 7 * PAIR2);     // C0..C3
            ve.i4 = *(const int4*)(q + 7 * PAIR2 + 4); // C4,C5,D0,D1
            vf.i4 = *(const int4*)(q + 7 * PAIR2 + 8); // D2..D5

            const __half2 A0 = va.h[0], A1 = va.h[1], A2 = va.h[2], A3 = va.h[3];
            const __half2 A4 = vb.h[0], A5 = vb.h[1];
            const __half2 B0 = vb.h[2], B1 = vb.h[3];
            const __half2 B2 = vc.h[0], B3 = vc.h[1], B4 = vc.h[2], B5 = vc.h[3];
            const __half2 C0 = vd.h[0], C1 = vd.h[1], C2 = vd.h[2], C3 = vd.h[3];
            const __half2 C4 = ve.h[0], C5 = ve.h[1];
            const __half2 D0 = ve.h[2], D1 = ve.h[3];
            const __half2 D2 = vf.h[0], D3 = vf.h[1], D4 = vf.h[2], D5 = vf.h[3];

            const __half2 r0 = __hfma2(w00, A0, __hfma2(w10, B0, __hfma2(w01, C0, __hmul2(w11, D0))));
            const __half2 r1 = __hfma2(w00, A1, __hfma2(w10, B1, __hfma2(w01, C1, __hmul2(w11, D1))));
            const __half2 r2 = __hfma2(w00, A2, __hfma2(w10, B2, __hfma2(w01, C2, __hmul2(w11, D2))));
            const __half2 r3 = __hfma2(w00, A3, __hfma2(w10, B3, __hfma2(w01, C3, __hmul2(w11, D3))));
            const __half2 r4 = __hfma2(w00, A4, __hfma2(w10, B4, __hfma2(w01, C4, __hmul2(w11, D4))));
            const __half2 r5 = __hfma2(w00, A5, __hfma2(w10, B5, __hfma2(w01, C5, __hmul2(w11, D5))));
            // r0=(A00,A10) r1=(A01,A11) r2=(A02,A12) r3=(A03,A13) r4=(A20,A21) r5=(A22,A23)

            const __half i0h = __float2half_rn(ia[k]);
            const __half i1h = __float2half_rn(ja[k]);
            const __half i2h = __float2half_rn(ka[k]);
            const __half2 bi0 = __half2half2(i0h);
            const __half2 bi1 = __half2half2(i1h);
            const __half2 bi2 = __half2half2(i2h);

            const __half2 acc01 = __hfma2(bi0, r0, __hfma2(bi1, r1, __hfma2(bi2, r2, r3)));
            const __half2 d2 = __hfma2(__halves2half2(i0h, i1h), r4,
                                       __hmul2(__halves2half2(i2h, oneh), r5));

            ok0[k] = __low2float(acc01);
            ok1[k] = __high2float(acc01);
            ok2[k] = __half2float(__hadd(__low2half(d2), __high2half(d2)));
        }

        *(f4*)&out[ib]             = f4{ok0[0], ok0[1], ok0[2], ok0[3]};
        *(f4*)&out[ib + plane]     = f4{ok1[0], ok1[1], ok1[2], ok1[3]};
        *(f4*)&out[ib + 2 * plane] = f4{ok2[0], ok2[1], ok2[2], ok2[3]};

        // ---- build next tile's Hs (program-order after this tile's reads;
        // per-wave in-order DS pipe makes single-buffer safe, no barrier) ----
        if (t < NTILE - 1) {
            build_hs(t + 1);
            cg = ng; ci0 = ni0; ci1 = ni1; ci2 = ni2;
        }
    }
}

extern "C" void kernel_launch(void* const* d_in, const int* in_sizes, int n_in,
                              void* d_out, int out_size, void* d_ws, size_t ws_size,
                              hipStream_t stream) {
    const float* grid  = (const float*)d_in[0];
    const float* guide = (const float*)d_in[1];
    const float* image = (const float*)d_in[2];
    float* out = (float*)d_out;

    dim3 block(16, 16, 1);
    dim3 grid_dim(WW / 64, HH / 32, BATCH);
    bsa_kernel<<<grid_dim, block, 0, stream>>>(grid, guide, image, out);
}

// Round 9
// 24.344 us; speedup vs baseline: 1.1173x; 1.1173x over previous
//
#include <hip/hip_runtime.h>
#include <hip/hip_fp16.h>

#define BATCH 4
#define HH 1024
#define WW 1024
#define GDp 8
#define NC 12
#define PAIR2 12    // half2 per z-pair cell: cells (z=p, z=p+1), 48 B, 16-B aligned
#define NXS 6       // staged x-cells: 256 px span 4 cells, +1 left +1 right
#define HROW2 504   // half2 per Hs row: 42 pairs * 12 = 504 (mult of 8 -> 16B rows)
#define NTILE 4     // 256x4 tiles per block (one 256x16 column)

union V4 { int4 i4; __half2 h[4]; };
typedef float f4 __attribute__((ext_vector_type(4)));

// Round-9: 256(x) x 4(y) tiles -> WAVE = ONE PIXEL ROW with float4 IO kept.
// r7's wave spanned 4 Hs rows x 2 xs0 x random zp => ~25 distinct b128 addrs
// over 8 bank groups -> measured 2.5M conflict cycles (~10K cyc/CU, the
// largest unhidden cost since reads are L3-served, writes ~8us HBM).
// One-row waves cut distinct addrs to ~12-15 (~2/group, near-free), and one
// Hs row (42 z-pairs) serves 256 px instead of 64 -> build cost/px drops 2.4x.
// Same r7 skeleton: barrier-free wave-local build, dbuf, build-ahead,
// persistent 256x16 column, 1024 blocks = 4/CU, LDS 23 KB.
__global__ __launch_bounds__(256, 4) void bsa_kernel(
    const float* __restrict__ grid,
    const float* __restrict__ guide,
    const float* __restrict__ image,
    float* __restrict__ out)
{
    __shared__ float sg[GDp][3][NXS][NC];                // 6912 B
    __shared__ __align__(16) __half2 Hs2[2][4][HROW2];   // 2 x 4 rows x 2016 B = 16128 B

    const int bx  = blockIdx.x;   // 0..3   (256-px x tiles)
    const int byc = blockIdx.y;   // 0..63  (16-row column)
    const int b   = blockIdx.z;
    const int tid  = threadIdx.y * 16 + threadIdx.x;
    const int lane = tid & 63;
    const int wv   = tid >> 6;    // wave id = row within tile; owns Hs2[.][wv]

    const int x0  = bx * 256;
    const int y0c = byc * 16;
    const float inv64 = 1.0f / 64.0f;

    // Column y-cell base: rows y0c..y0c+15 have floor(gy) in {ylo, ylo+1}.
    const float gy0c = (y0c + 0.5f) * inv64 - 0.5f;
    const int ylo = (int)floorf(gy0c);

    const int xloc = 4 * lane;
    const size_t plane = (size_t)HH * WW;
    const size_t gpix0 = ((size_t)(b * HH + y0c + wv)) * WW + x0 + xloc;
    const size_t ib0   = (size_t)b * 3 * plane + (size_t)(y0c + wv) * WW + x0 + xloc;

    // ---- tile-0 pixel IO: in flight under staging + build ----
    f4 cg  = *(const f4*)&guide[gpix0];
    f4 ci0 = *(const f4*)&image[ib0];
    f4 ci1 = *(const f4*)&image[ib0 + plane];
    f4 ci2 = *(const f4*)&image[ib0 + 2 * plane];

    // ---- stage grid slice once per block: 6 x-cells, o-pack channel permute ----
    for (int e = tid; e < 432; e += 256) {            // 432 = 8z * 54 quad-units
        const int z  = e / 54;
        const int u  = e - z * 54;
        const int cell = (u * 171) >> 9;              // u/3   (exact for u<54)
        const int cq   = u - cell * 3;
        const int yy   = (cell * 11) >> 6;            // cell/6 (exact for cell<18)
        const int xx   = cell - yy * 6;
        const int gxi = min(max(4 * bx - 1 + xx, 0), 15);
        const int gyi = min(max(ylo + yy, 0), 15);
        const float* gp = grid + (size_t)b * (NC * GDp * 256)
                               + ((size_t)z * 16 + gyi) * 16 + gxi;
#pragma unroll
        for (int j = 0; j < 4; ++j) {
            const int c = cq * 4 + j;
            // o-pack perm: pairs (c0,c4)(c1,c5)(c2,c6)(c3,c7)(c8,c9)(c10,c11)
            const int pos = (c < 8) ? ((c & 3) * 2 + (c >> 2)) : c;
            sg[z][yy][xx][pos] = gp[(size_t)c * (GDp * 256)];
        }
    }
    __syncthreads();   // the ONLY block-wide barrier

    // ---- wave-local Hs build: wave wv builds ITS row of tile t (48 cells) ----
    auto build_hs = [&](int buf, int t) {
        if (lane < 48) {
            const int xs = lane >> 3;    // 0..5
            const int z  = lane & 7;
            const float gy  = (y0c + t * 4 + wv + 0.5f) * inv64 - 0.5f;
            const float fyf = floorf(gy);
            const float wy1 = gy - fyf;
            const float wy0 = 1.0f - wy1;
            const int ys0 = (int)fyf - ylo;          // 0 or 1 (column-wide)
            const float* s0 = &sg[z][ys0][xs][0];
            const float* s1 = &sg[z][ys0 + 1][xs][0];
            __half2 h[6];
#pragma unroll
            for (int m = 0; m < 6; ++m) {
                h[m] = __floats2half2_rn(wy0 * s0[2*m]   + wy1 * s1[2*m],
                                         wy0 * s0[2*m+1] + wy1 * s1[2*m+1]);
            }
            __half2* rowp = &Hs2[buf][wv][0];
            if (z < 7) {                 // first half of pair p = xs*7+z
                __half2* hd = rowp + (xs * 7 + z) * PAIR2;
#pragma unroll
                for (int m = 0; m < 6; ++m) hd[m] = h[m];
            }
            if (z > 0) {                 // second half of pair p = xs*7+z-1
                __half2* hd = rowp + (xs * 7 + (z - 1)) * PAIR2 + 6;
#pragma unroll
                for (int m = 0; m < 6; ++m) hd[m] = h[m];
            }
        }
    };

    build_hs(0, 0);    // in-wave lgkmcnt orders writes before this wave's reads

    // ---- per-thread x-interp constants ----
    // cell boundary sits between local px 31|32, 95|96, ... -> xs0=(lane+8)>>4
    const int xs0 = (lane + 8) >> 4;             // 0..4
    const float fxf = (float)(4 * bx - 1 + xs0);
    const float gxb = (x0 + xloc + 0.5f) * inv64 - 0.5f;
    const __half oneh = __float2half_rn(1.0f);

#pragma unroll
    for (int t = 0; t < NTILE; ++t) {
        // ---- prefetch next tile's pixel IO (static regs; stays in flight) ----
        f4 ng, ni0, ni1, ni2;
        if (t < NTILE - 1) {
            const size_t gp = gpix0 + (size_t)(t + 1) * 4 * WW;
            const size_t ip = ib0   + (size_t)(t + 1) * 4 * WW;
            ng  = *(const f4*)&guide[gp];
            ni0 = *(const f4*)&image[ip];
            ni1 = *(const f4*)&image[ip + plane];
            ni2 = *(const f4*)&image[ip + 2 * plane];
        }

        // ---- build next tile's Hs (wave-local row, other buffer, no barrier) ----
        if (t < NTILE - 1) build_hs((t + 1) & 1, t + 1);

        // ---- per-pixel compute: 4 adjacent x px/thread, one row per wave ----
        const __half2* Hrow = &Hs2[t & 1][wv][0];
        const size_t ib = ib0 + (size_t)t * 4 * WW;

        const float gk[4]  = {cg.x, cg.y, cg.z, cg.w};
        const float ia[4]  = {ci0.x, ci0.y, ci0.z, ci0.w};
        const float ja[4]  = {ci1.x, ci1.y, ci1.z, ci1.w};
        const float ka[4]  = {ci2.x, ci2.y, ci2.z, ci2.w};
        float ok0[4], ok1[4], ok2[4];

#pragma unroll
        for (int k = 0; k < 4; ++k) {
            const float wx1 = (gxb - fxf) + (float)k * inv64;
            const float wx0 = 1.0f - wx1;

            const float gz  = fmaf(gk[k], 8.0f, -0.5f);
            const float fzf = floorf(gz);
            const float zpf = fminf(fmaxf(fzf, 0.0f), 6.0f);      // v_med3
            const float whi = fminf(fmaxf(gz - zpf, 0.0f), 1.0f); // v_med3
            const float wlo = 1.0f - whi;
            const int zp = (int)zpf;

            const __half2 w00 = __float2half2_rn(wx0 * wlo);
            const __half2 w10 = __float2half2_rn(wx0 * whi);
            const __half2 w01 = __float2half2_rn(wx1 * wlo);
            const __half2 w11 = __float2half2_rn(wx1 * whi);

            // z-pair layout: 6 aligned ds_read_b128; C/D pair is xs0+1 (=+7 pairs)
            const __half2* q = Hrow + (xs0 * 7 + zp) * PAIR2;
            V4 va, vb, vc, vd, ve, vf;
            va.i4 = *(const int4*)(q);           // A0..A3
            vb.i4 = *(const int4*)(q + 4);       // A4,A5,B0,B1
            vc.i4 = *(const int4*)(q + 8);       // B2..B5
            vd.i4 = *(const int4*)(q + 7 * PAIR2);     // C0..C3
            ve.i4 = *(const int4*)(q + 7 * PAIR2 + 4); // C4,C5,D0,D1
            vf.i4 = *(const int4*)(q + 7 * PAIR2 + 8); // D2..D5

            const __half2 A0 = va.h[0], A1 = va.h[1], A2 = va.h[2], A3 = va.h[3];
            const __half2 A4 = vb.h[0], A5 = vb.h[1];
            const __half2 B0 = vb.h[2], B1 = vb.h[3];
            const __half2 B2 = vc.h[0], B3 = vc.h[1], B4 = vc.h[2], B5 = vc.h[3];
            const __half2 C0 = vd.h[0], C1 = vd.h[1], C2 = vd.h[2], C3 = vd.h[3];
            const __half2 C4 = ve.h[0], C5 = ve.h[1];
            const __half2 D0 = ve.h[2], D1 = ve.h[3];
            const __half2 D2 = vf.h[0], D3 = vf.h[1], D4 = vf.h[2], D5 = vf.h[3];

            const __half2 r0 = __hfma2(w00, A0, __hfma2(w10, B0, __hfma2(w01, C0, __hmul2(w11, D0))));
            const __half2 r1 = __hfma2(w00, A1, __hfma2(w10, B1, __hfma2(w01, C1, __hmul2(w11, D1))));
            const __half2 r2 = __hfma2(w00, A2, __hfma2(w10, B2, __hfma2(w01, C2, __hmul2(w11, D2))));
            const __half2 r3 = __hfma2(w00, A3, __hfma2(w10, B3, __hfma2(w01, C3, __hmul2(w11, D3))));
            const __half2 r4 = __hfma2(w00, A4, __hfma2(w10, B4, __hfma2(w01, C4, __hmul2(w11, D4))));
            const __half2 r5 = __hfma2(w00, A5, __hfma2(w10, B5, __hfma2(w01, C5, __hmul2(w11, D5))));
            // r0=(A00,A10) r1=(A01,A11) r2=(A02,A12) r3=(A03,A13) r4=(A20,A21) r5=(A22,A23)

            const __half i0h = __float2half_rn(ia[k]);
            const __half i1h = __float2half_rn(ja[k]);
            const __half i2h = __float2half_rn(ka[k]);
            const __half2 bi0 = __half2half2(i0h);
            const __half2 bi1 = __half2half2(i1h);
            const __half2 bi2 = __half2half2(i2h);

            const __half2 acc01 = __hfma2(bi0, r0, __hfma2(bi1, r1, __hfma2(bi2, r2, r3)));
            const __half2 d2 = __hfma2(__halves2half2(i0h, i1h), r4,
                                       __hmul2(__halves2half2(i2h, oneh), r5));

            ok0[k] = __low2float(acc01);
            ok1[k] = __high2float(acc01);
            ok2[k] = __half2float(__hadd(__low2half(d2), __high2half(d2)));
        }

        *(f4*)&out[ib]             = f4{ok0[0], ok0[1], ok0[2], ok0[3]};
        *(f4*)&out[ib + plane]     = f4{ok1[0], ok1[1], ok1[2], ok1[3]};
        *(f4*)&out[ib + 2 * plane] = f4{ok2[0], ok2[1], ok2[2], ok2[3]};

        if (t < NTILE - 1) { cg = ng; ci0 = ni0; ci1 = ni1; ci2 = ni2; }
    }
}

extern "C" void kernel_launch(void* const* d_in, const int* in_sizes, int n_in,
                              void* d_out, int out_size, void* d_ws, size_t ws_size,
                              hipStream_t stream) {
    const float* grid  = (const float*)d_in[0];
    const float* guide = (const float*)d_in[1];
    const float* image = (const float*)d_in[2];
    float* out = (float*)d_out;

    dim3 block(16, 16, 1);
    dim3 grid_dim(WW / 256, HH / 16, BATCH);
    bsa_kernel<<<grid_dim, block, 0, stream>>>(grid, guide, image, out);
}